// Round 1
// baseline (227.657 us; speedup 1.0000x reference)
//
#include <hip/hip_runtime.h>

// Segment-mean over a sorted ragged batch.
//   x:            [N, D] float32   (N = 1e6, D = 256)
//   segment_ids:  [N]    int32, SORTED ascending in [0, B)
//   out:          [B, D] float32   (B = 16)
//
// Memory-bound: 1.028 GB read -> ~163 us floor at 6.3 TB/s.
// Strategy: contiguous row-chunk per block, one wave per row per iteration
// (64 lanes x float4 = 1 KiB = one full row, perfectly coalesced),
// register accumulation keyed on the (sorted, hence rarely-changing)
// segment id, rare atomicAdd flushes into a 16 KB workspace accumulator.

constexpr int D = 256;   // feature dim
constexpr int B = 16;    // number of segments

__global__ void zero_ws_kernel(float* __restrict__ ws, int n) {
    int i = blockIdx.x * blockDim.x + threadIdx.x;
    if (i < n) ws[i] = 0.0f;
}

__device__ __forceinline__ void flush_acc(int cur, const float4& acc, int cnt,
                                          int lane, float* __restrict__ sums,
                                          float* __restrict__ counts) {
    if (cur < 0 || cnt == 0) return;
    float* p = sums + cur * D + lane * 4;
    atomicAdd(p + 0, acc.x);
    atomicAdd(p + 1, acc.y);
    atomicAdd(p + 2, acc.z);
    atomicAdd(p + 3, acc.w);
    if (lane == 0) atomicAdd(counts + cur, (float)cnt);
}

__global__ __launch_bounds__(256) void seg_sum_kernel(
        const float4* __restrict__ x, const int* __restrict__ seg,
        float* __restrict__ sums, float* __restrict__ counts, int N) {
    const int lane = threadIdx.x & 63;   // owns features [lane*4, lane*4+4)
    const int wave = threadIdx.x >> 6;   // 4 waves/block, one row each per iter

    // Contiguous chunk of rows per block => few segment transitions per wave.
    const int rowsPerBlock = (N + gridDim.x - 1) / gridDim.x;
    const int r0 = blockIdx.x * rowsPerBlock;
    const int r1 = min(N, r0 + rowsPerBlock);

    float4 acc = make_float4(0.f, 0.f, 0.f, 0.f);
    int cur = -1;
    int cnt = 0;

    for (int r = r0 + wave; r < r1; r += 4) {
        int s = seg[r];  // wave-uniform load (all lanes same address)
        float4 v = x[(long long)r * (D / 4) + lane];
        if (s != cur) {  // uniform branch, fires <= ~2 times per wave
            flush_acc(cur, acc, cnt, lane, sums, counts);
            acc = make_float4(0.f, 0.f, 0.f, 0.f);
            cnt = 0;
            cur = s;
        }
        acc.x += v.x; acc.y += v.y; acc.z += v.z; acc.w += v.w;
        ++cnt;
    }
    flush_acc(cur, acc, cnt, lane, sums, counts);
}

__global__ void finalize_kernel(const float* __restrict__ sums,
                                const float* __restrict__ counts,
                                float* __restrict__ out) {
    int i = blockIdx.x * blockDim.x + threadIdx.x;
    if (i < B * D) {
        int b = i >> 8;  // i / D (D == 256)
        out[i] = sums[i] / fmaxf(counts[b], 1.0f);
    }
}

extern "C" void kernel_launch(void* const* d_in, const int* in_sizes, int n_in,
                              void* d_out, int out_size, void* d_ws, size_t ws_size,
                              hipStream_t stream) {
    const float4* x  = (const float4*)d_in[0];      // [N, D] fp32
    const int*   seg = (const int*)d_in[1];         // [N] int32, sorted
    float*       out = (float*)d_out;               // [B, D] fp32

    const int N = in_sizes[1];                      // 1e6 rows

    // Workspace accumulators: sums [B*D] then counts [B]. Must be zeroed
    // every call (harness poisons once, never re-poisons between replays).
    float* sums   = (float*)d_ws;
    float* counts = sums + B * D;
    const int nws = B * D + B;
    zero_ws_kernel<<<(nws + 255) / 256, 256, 0, stream>>>(sums, nws);

    // 1024 blocks x 256 threads = 4096 waves (16/CU) — enough TLP to
    // saturate HBM while keeping atomic flushes ~1M total.
    const int blocks = 1024;
    seg_sum_kernel<<<blocks, 256, 0, stream>>>(x, seg, sums, counts, N);

    finalize_kernel<<<(B * D + 255) / 256, 256, 0, stream>>>(sums, counts, out);
}